// Round 3
// baseline (424.178 us; speedup 1.0000x reference)
//
#include <hip/hip_runtime.h>
#include <hip/hip_bf16.h>
#include <math.h>

typedef __attribute__((ext_vector_type(8))) short short8;
typedef __attribute__((ext_vector_type(4))) float f32x4;
typedef unsigned short ushort_t;

__device__ __forceinline__ ushort_t f2bf(float f) {
    union { float f; unsigned u; } v; v.f = f;
    unsigned r = v.u + 0x7FFF + ((v.u >> 16) & 1);
    return (ushort_t)(r >> 16);
}
__device__ __forceinline__ float bf2f(short s) {
    union { unsigned u; float f; } v; v.u = ((unsigned)(ushort_t)s) << 16;
    return v.f;
}

// ---------------- fp32 -> bf16 convert (x) ----------------
__global__ void cvt_kernel(const float* __restrict__ src, ushort_t* __restrict__ dst, int n8) {
    int i = blockIdx.x * blockDim.x + threadIdx.x;
    int stride = gridDim.x * blockDim.x;
    for (; i < n8; i += stride) {
        const float4* s = reinterpret_cast<const float4*>(src) + (size_t)i * 2;
        float4 a = s[0], b = s[1];
        short8 o;
        o[0] = (short)f2bf(a.x); o[1] = (short)f2bf(a.y);
        o[2] = (short)f2bf(a.z); o[3] = (short)f2bf(a.w);
        o[4] = (short)f2bf(b.x); o[5] = (short)f2bf(b.y);
        o[6] = (short)f2bf(b.z); o[7] = (short)f2bf(b.w);
        reinterpret_cast<short8*>(dst)[i] = o;
    }
}

// ---------------- fused weight convert: wq|wk|wv|wo -> contiguous bf16 ----------------
__global__ void cvtw_kernel(const float* __restrict__ w0, const float* __restrict__ w1,
                            const float* __restrict__ w2, const float* __restrict__ w3,
                            ushort_t* __restrict__ dst, int dd8) {
    int i = blockIdx.x * blockDim.x + threadIdx.x;
    int stride = gridDim.x * blockDim.x;
    const int total = dd8 * 4;
    for (; i < total; i += stride) {
        int which = i / dd8;
        int off = i - which * dd8;
        const float* src = (which == 0) ? w0 : (which == 1) ? w1 : (which == 2) ? w2 : w3;
        const float4* s = reinterpret_cast<const float4*>(src) + (size_t)off * 2;
        float4 a = s[0], b = s[1];
        short8 o;
        o[0] = (short)f2bf(a.x); o[1] = (short)f2bf(a.y);
        o[2] = (short)f2bf(a.z); o[3] = (short)f2bf(a.w);
        o[4] = (short)f2bf(b.x); o[5] = (short)f2bf(b.y);
        o[6] = (short)f2bf(b.z); o[7] = (short)f2bf(b.w);
        reinterpret_cast<short8*>(dst)[i] = o;
    }
}

// ---------------- GEMM NT (m97 structure + XCD swizzle) ----------------
// 128x128 tile, BK=32, 256 threads = 4 waves (2x2). Requires (M/128)*(N/128) % 8 == 0.
template<int OUT_BF16>
__global__ __launch_bounds__(256) void gemm_nt(const ushort_t* __restrict__ A,
                                               const ushort_t* __restrict__ Bw,
                                               void* __restrict__ Cout,
                                               int M, int N, int K) {
    __shared__ __align__(16) ushort_t As[128 * 32];
    __shared__ __align__(16) ushort_t Bs[128 * 32];
    const int t = threadIdx.x;
    const int wid = t >> 6, lane = t & 63;
    const int wm = wid >> 1, wn = wid & 1;
    const int lr = lane & 15, lg = lane >> 4;

    // XCD-aware bijective swizzle (nwg % 8 == 0)
    const int ntc = N >> 7;
    const int nwg = (M >> 7) * ntc;
    const int bid = blockIdx.y * gridDim.x + blockIdx.x;
    const int cpx = nwg >> 3;
    const int swz = (bid & 7) * cpx + (bid >> 3);
    const int m0 = (swz / ntc) * 128, n0 = (swz % ntc) * 128;

    f32x4 acc[4][4] = {};

    const int sh0 = wid * 1024 + lane * 8;
    const int sh1 = sh0 + 512;
    const int r0 = sh0 >> 5, c0 = sh0 & 31;
    const int r1 = sh1 >> 5, c1 = sh1 & 31;

    const ushort_t* gA0 = A + (long)(m0 + r0) * K + c0;
    const ushort_t* gA1 = A + (long)(m0 + r1) * K + c1;
    const ushort_t* gB0 = Bw + (long)(n0 + r0) * K + c0;
    const ushort_t* gB1 = Bw + (long)(n0 + r1) * K + c1;

    for (int k0 = 0; k0 < K; k0 += 32) {
        __syncthreads();
        __builtin_amdgcn_global_load_lds((const __attribute__((address_space(1))) unsigned int*)(gA0 + k0),
                                         (__attribute__((address_space(3))) unsigned int*)(As + sh0), 16, 0, 0);
        __builtin_amdgcn_global_load_lds((const __attribute__((address_space(1))) unsigned int*)(gA1 + k0),
                                         (__attribute__((address_space(3))) unsigned int*)(As + sh1), 16, 0, 0);
        __builtin_amdgcn_global_load_lds((const __attribute__((address_space(1))) unsigned int*)(gB0 + k0),
                                         (__attribute__((address_space(3))) unsigned int*)(Bs + sh0), 16, 0, 0);
        __builtin_amdgcn_global_load_lds((const __attribute__((address_space(1))) unsigned int*)(gB1 + k0),
                                         (__attribute__((address_space(3))) unsigned int*)(Bs + sh1), 16, 0, 0);
        __syncthreads();
        short8 af[4], bfr[4];
        #pragma unroll
        for (int m = 0; m < 4; ++m)
            af[m] = *reinterpret_cast<const short8*>(&As[(wm * 64 + m * 16 + lr) * 32 + lg * 8]);
        #pragma unroll
        for (int n = 0; n < 4; ++n)
            bfr[n] = *reinterpret_cast<const short8*>(&Bs[(wn * 64 + n * 16 + lr) * 32 + lg * 8]);
        #pragma unroll
        for (int m = 0; m < 4; ++m)
            #pragma unroll
            for (int n = 0; n < 4; ++n)
                acc[m][n] = __builtin_amdgcn_mfma_f32_16x16x32_bf16(af[m], bfr[n], acc[m][n], 0, 0, 0);
    }
    #pragma unroll
    for (int m = 0; m < 4; ++m) {
        #pragma unroll
        for (int n = 0; n < 4; ++n) {
            #pragma unroll
            for (int r = 0; r < 4; ++r) {
                int row = m0 + wm * 64 + m * 16 + lg * 4 + r;
                int col = n0 + wn * 64 + n * 16 + lr;
                float v = acc[m][n][r];
                if (OUT_BF16)
                    ((ushort_t*)Cout)[(long)row * N + col] = f2bf(v);
                else
                    ((float*)Cout)[(long)row * N + col] = v;
            }
        }
    }
}

// ---------------- RoPE on fused QKV matrix (cols < 4096 of M x 6144), in place ----------------
__global__ void rope_kernel(ushort_t* __restrict__ X, const float* __restrict__ fc,
                            const float* __restrict__ fs, int total8) {
    int i = blockIdx.x * blockDim.x + threadIdx.x;
    if (i >= total8) return;
    const int row = i >> 9;            // M*512 vec8s, 512 per row (cols 0..4095)
    const int col8 = i & 511;
    const int s_idx = row & 2047;      // row = b*2048 + s
    const long base = (long)row * 6144 + col8 * 8;
    const int i0 = (col8 & 15) * 4;    // ((col*8)&127)>>1
    short8 v = *reinterpret_cast<const short8*>(X + base);
    short8 o;
    #pragma unroll
    for (int p = 0; p < 4; ++p) {
        float c  = fc[(long)s_idx * 64 + i0 + p];
        float sn = fs[(long)s_idx * 64 + i0 + p];
        float x0 = bf2f(v[2 * p]), x1 = bf2f(v[2 * p + 1]);
        o[2 * p]     = (short)f2bf(x0 * c - x1 * sn);
        o[2 * p + 1] = (short)f2bf(x0 * sn + x1 * c);
    }
    *reinterpret_cast<short8*>(X + base) = o;
}

// ---------------- V transpose: fused QKV cols 4096..6143 -> Vt[B*H, 128, S] ----------------
__global__ void vtrans_kernel(const ushort_t* __restrict__ QKV, ushort_t* __restrict__ Vt,
                              int S, int H) {
    const int bh = blockIdx.y;
    const int b = bh / H, h = bh % H;
    const int s0 = blockIdx.x * 16 + ((threadIdx.x >> 7) * 8);
    const int d = threadIdx.x & 127;
    const ushort_t* src = QKV + (long)b * S * 6144 + 4096 + h * 128 + d;
    short8 o;
    #pragma unroll
    for (int i = 0; i < 8; ++i)
        o[i] = (short)src[(long)(s0 + i) * 6144];
    *reinterpret_cast<short8*>(Vt + ((long)bh * 128 + d) * S + s0) = o;
}

// ---------------- causal flash attention (KVB=64, 1 q-tile/block, longest-first) ----------------
__global__ __launch_bounds__(256) void attn_kernel(const ushort_t* __restrict__ QKV,
                                                   const ushort_t* __restrict__ Vtg,
                                                   ushort_t* __restrict__ O,
                                                   int S, int H) {
    __shared__ __align__(16) ushort_t Ks[64][136];
    __shared__ __align__(16) ushort_t Vs[128][72];
    __shared__ __align__(16) ushort_t Pl[4][16][72];
    const int t = threadIdx.x, wid = t >> 6, lane = t & 63;
    const int lr = lane & 15, lg = lane >> 4;
    const int bh = blockIdx.y;
    const int b = bh / H, h = bh % H;
    const ushort_t* Qh = QKV + (long)b * S * 6144 + h * 128;
    const ushort_t* Kh = Qh + 2048;
    const ushort_t* Vth = Vtg + (long)bh * 128 * S;
    const int nq = S / 64;
    const int qt = nq - 1 - blockIdx.x;     // longest blocks dispatch first
    const int qb0 = qt * 64;
    const float scale = 0.08838834764831845f;

    const int ksr = t >> 2;
    const int ksc = (t & 3) * 32;
    const int vsr = t & 127;
    const int vsc = (t >> 7) * 32;

    const int qrow = qb0 + wid * 16 + lr;
    short8 qf[4];
    #pragma unroll
    for (int kk = 0; kk < 4; ++kk)
        qf[kk] = *reinterpret_cast<const short8*>(Qh + (long)qrow * 6144 + kk * 32 + lg * 8);

    f32x4 oacc[8] = {};
    float mrow[4], lsum[4];
    #pragma unroll
    for (int r = 0; r < 4; ++r) { mrow[r] = -INFINITY; lsum[r] = 0.f; }

    const int nkt = qt + 1;
    for (int kt = 0; kt < nkt; ++kt) {
        const int kv0 = kt * 64;
        __syncthreads();
        const ushort_t* kgp = Kh + (long)(kv0 + ksr) * 6144 + ksc;
        #pragma unroll
        for (int j = 0; j < 4; ++j)
            *reinterpret_cast<short8*>(&Ks[ksr][ksc + j * 8]) = *reinterpret_cast<const short8*>(kgp + j * 8);
        const ushort_t* vgp = Vth + (long)vsr * S + kv0 + vsc;
        #pragma unroll
        for (int j = 0; j < 4; ++j)
            *reinterpret_cast<short8*>(&Vs[vsr][vsc + j * 8]) = *reinterpret_cast<const short8*>(vgp + j * 8);
        __syncthreads();

        f32x4 sacc[4] = {};
        #pragma unroll
        for (int kk = 0; kk < 4; ++kk) {
            #pragma unroll
            for (int n = 0; n < 4; ++n) {
                short8 kf = *reinterpret_cast<const short8*>(&Ks[n * 16 + lr][kk * 32 + lg * 8]);
                sacc[n] = __builtin_amdgcn_mfma_f32_16x16x32_bf16(qf[kk], kf, sacc[n], 0, 0, 0);
            }
        }
        float sv[4][4];
        const int myq = qb0 + wid * 16 + lg * 4;
        #pragma unroll
        for (int n = 0; n < 4; ++n) {
            int kcol = kv0 + n * 16 + lr;
            #pragma unroll
            for (int r = 0; r < 4; ++r) {
                float xv = sacc[n][r] * scale;
                sv[n][r] = (kcol > myq + r) ? -1e9f : xv;
            }
        }
        float alpha[4];
        #pragma unroll
        for (int r = 0; r < 4; ++r) {
            float mx = fmaxf(fmaxf(sv[0][r], sv[1][r]), fmaxf(sv[2][r], sv[3][r]));
            #pragma unroll
            for (int off = 1; off < 16; off <<= 1)
                mx = fmaxf(mx, __shfl_xor(mx, off));
            float mnew = fmaxf(mrow[r], mx);
            alpha[r] = __expf(mrow[r] - mnew);
            float ts = 0.f;
            #pragma unroll
            for (int n = 0; n < 4; ++n) {
                float p = __expf(sv[n][r] - mnew);
                sv[n][r] = p;
                ts += p;
            }
            #pragma unroll
            for (int off = 1; off < 16; off <<= 1)
                ts += __shfl_xor(ts, off);
            lsum[r] = lsum[r] * alpha[r] + ts;
            mrow[r] = mnew;
        }
        #pragma unroll
        for (int f = 0; f < 8; ++f)
            #pragma unroll
            for (int r = 0; r < 4; ++r)
                oacc[f][r] *= alpha[r];
        #pragma unroll
        for (int n = 0; n < 4; ++n)
            #pragma unroll
            for (int r = 0; r < 4; ++r)
                Pl[wid][lg * 4 + r][n * 16 + lr] = f2bf(sv[n][r]);
        __asm volatile("" ::: "memory");
        short8 pf[2];
        #pragma unroll
        for (int ks = 0; ks < 2; ++ks)
            pf[ks] = *reinterpret_cast<const short8*>(&Pl[wid][lr][ks * 32 + lg * 8]);
        #pragma unroll
        for (int f = 0; f < 8; ++f) {
            #pragma unroll
            for (int ks = 0; ks < 2; ++ks) {
                short8 vf = *reinterpret_cast<const short8*>(&Vs[f * 16 + lr][ks * 32 + lg * 8]);
                oacc[f] = __builtin_amdgcn_mfma_f32_16x16x32_bf16(pf[ks], vf, oacc[f], 0, 0, 0);
            }
        }
    }
    float inv[4];
    #pragma unroll
    for (int r = 0; r < 4; ++r) inv[r] = 1.f / lsum[r];
    ushort_t* Oh = O + (long)b * S * 2048 + h * 128;
    #pragma unroll
    for (int f = 0; f < 8; ++f) {
        #pragma unroll
        for (int r = 0; r < 4; ++r) {
            int row = qb0 + wid * 16 + lg * 4 + r;
            int col = f * 16 + lr;
            Oh[(long)row * 2048 + col] = f2bf(oacc[f][r] * inv[r]);
        }
    }
}

extern "C" void kernel_launch(void* const* d_in, const int* in_sizes, int n_in,
                              void* d_out, int out_size, void* d_ws, size_t ws_size,
                              hipStream_t stream) {
    const float* x  = (const float*)d_in[0];
    const float* fc = (const float*)d_in[1];
    const float* fs = (const float*)d_in[2];
    const float* wq = (const float*)d_in[3];
    const float* wk = (const float*)d_in[4];
    const float* wv = (const float*)d_in[5];
    const float* wo = (const float*)d_in[6];
    float* out = (float*)d_out;

    const int B = 2, S = 2048, D = 2048, H = 16;
    const int M = B * S;            // 4096
    const size_t MD = (size_t)M * D;
    const size_t DD = (size_t)D * D;

    char* ws = (char*)d_ws;
    ushort_t* xbf = (ushort_t*)ws;                    // [0, 16.8MB)
    ushort_t* wqb = (ushort_t*)(ws + MD * 2);         // 4 weights contiguous: wq|wk|wv|wo
    ushort_t* wob = wqb + 3 * DD;
    ushort_t* qkv = wqb + 4 * DD;                     // M x 6144 fused output
    ushort_t* vtg   = xbf;                            // overlay: x dead after QKV GEMM
    ushort_t* attnb = wqb;                            // overlay: wq..wk bf16 dead after QKV GEMM (16.8MB)

    // 1) converts
    cvt_kernel<<<2048, 256, 0, stream>>>(x, xbf, (int)(MD / 8));
    cvtw_kernel<<<2048, 256, 0, stream>>>(wq, wk, wv, wo, wqb, (int)(DD / 8));

    // 2) fused QKV projection: C = x @ [wq|wk|wv]^T  (M x 6144)
    dim3 gq(6144 / 128, M / 128);
    gemm_nt<1><<<gq, 256, 0, stream>>>(xbf, wqb, qkv, M, 3 * D, D);

    // 3) RoPE on Q,K halves (cols < 4096)
    const int total8 = M * 512;
    rope_kernel<<<(total8 + 255) / 256, 256, 0, stream>>>(qkv, fc, fs, total8);

    // 4) V transpose, then causal flash attention
    dim3 gv(S / 16, B * H);
    vtrans_kernel<<<gv, 256, 0, stream>>>(qkv, vtg, S, H);
    dim3 ga(S / 64, B * H);
    attn_kernel<<<ga, 256, 0, stream>>>(qkv, vtg, attnb, S, H);

    // 5) output projection (fp32 out)
    dim3 gg(D / 128, M / 128);
    gemm_nt<0><<<gg, 256, 0, stream>>>(attnb, wob, out, M, D, D);
}

// Round 4
// 348.583 us; speedup vs baseline: 1.2169x; 1.2169x over previous
//
#include <hip/hip_runtime.h>
#include <hip/hip_bf16.h>
#include <math.h>

typedef __attribute__((ext_vector_type(8))) short short8;
typedef __attribute__((ext_vector_type(4))) float f32x4;
typedef unsigned short ushort_t;

__device__ __forceinline__ ushort_t f2bf(float f) {
    union { float f; unsigned u; } v; v.f = f;
    unsigned r = v.u + 0x7FFF + ((v.u >> 16) & 1);
    return (ushort_t)(r >> 16);
}
__device__ __forceinline__ float bf2f(short s) {
    union { unsigned u; float f; } v; v.u = ((unsigned)(ushort_t)s) << 16;
    return v.f;
}

// ---------------- fp32 -> bf16 convert (x) ----------------
__global__ void cvt_kernel(const float* __restrict__ src, ushort_t* __restrict__ dst, int n8) {
    int i = blockIdx.x * blockDim.x + threadIdx.x;
    int stride = gridDim.x * blockDim.x;
    for (; i < n8; i += stride) {
        const float4* s = reinterpret_cast<const float4*>(src) + (size_t)i * 2;
        float4 a = s[0], b = s[1];
        short8 o;
        o[0] = (short)f2bf(a.x); o[1] = (short)f2bf(a.y);
        o[2] = (short)f2bf(a.z); o[3] = (short)f2bf(a.w);
        o[4] = (short)f2bf(b.x); o[5] = (short)f2bf(b.y);
        o[6] = (short)f2bf(b.z); o[7] = (short)f2bf(b.w);
        reinterpret_cast<short8*>(dst)[i] = o;
    }
}

// ---------------- fused weight convert: wq|wk|wv|wo -> contiguous bf16 ----------------
__global__ void cvtw_kernel(const float* __restrict__ w0, const float* __restrict__ w1,
                            const float* __restrict__ w2, const float* __restrict__ w3,
                            ushort_t* __restrict__ dst, int dd8) {
    int i = blockIdx.x * blockDim.x + threadIdx.x;
    int stride = gridDim.x * blockDim.x;
    const int total = dd8 * 4;
    for (; i < total; i += stride) {
        int which = i / dd8;
        int off = i - which * dd8;
        const float* src = (which == 0) ? w0 : (which == 1) ? w1 : (which == 2) ? w2 : w3;
        const float4* s = reinterpret_cast<const float4*>(src) + (size_t)off * 2;
        float4 a = s[0], b = s[1];
        short8 o;
        o[0] = (short)f2bf(a.x); o[1] = (short)f2bf(a.y);
        o[2] = (short)f2bf(a.z); o[3] = (short)f2bf(a.w);
        o[4] = (short)f2bf(b.x); o[5] = (short)f2bf(b.y);
        o[6] = (short)f2bf(b.z); o[7] = (short)f2bf(b.w);
        reinterpret_cast<short8*>(dst)[i] = o;
    }
}

// ---------------- GEMM NT (m97 structure + XCD swizzle) ----------------
// 128x128 tile, BK=32, 256 threads = 4 waves (2x2). Requires (M/128)*(N/128) % 8 == 0.
// OUT_MODE 0: fp32 row-major [M,N]. OUT_MODE 1: bf16 head-packed: col c of N=6144
// belongs to matrix which=c>>11, head h=(c>>7)&15, d=c&127; row -> b=row>>11, s=row&2047;
// dst[which*M*2048 + ((b*16+h)*2048 + s)*128 + d]   (each 16-col group is head-uniform).
template<int OUT_MODE>
__global__ __launch_bounds__(256) void gemm_nt(const ushort_t* __restrict__ A,
                                               const ushort_t* __restrict__ Bw,
                                               void* __restrict__ Cout,
                                               int M, int N, int K) {
    __shared__ __align__(16) ushort_t As[128 * 32];
    __shared__ __align__(16) ushort_t Bs[128 * 32];
    const int t = threadIdx.x;
    const int wid = t >> 6, lane = t & 63;
    const int wm = wid >> 1, wn = wid & 1;
    const int lr = lane & 15, lg = lane >> 4;

    const int ntc = N >> 7;
    const int nwg = (M >> 7) * ntc;
    const int bid = blockIdx.y * gridDim.x + blockIdx.x;
    const int cpx = nwg >> 3;
    const int swz = (bid & 7) * cpx + (bid >> 3);
    const int m0 = (swz / ntc) * 128, n0 = (swz % ntc) * 128;

    f32x4 acc[4][4] = {};

    const int sh0 = wid * 1024 + lane * 8;
    const int sh1 = sh0 + 512;
    const int r0 = sh0 >> 5, c0 = sh0 & 31;
    const int r1 = sh1 >> 5, c1 = sh1 & 31;

    const ushort_t* gA0 = A + (long)(m0 + r0) * K + c0;
    const ushort_t* gA1 = A + (long)(m0 + r1) * K + c1;
    const ushort_t* gB0 = Bw + (long)(n0 + r0) * K + c0;
    const ushort_t* gB1 = Bw + (long)(n0 + r1) * K + c1;

    for (int k0 = 0; k0 < K; k0 += 32) {
        __syncthreads();
        __builtin_amdgcn_global_load_lds((const __attribute__((address_space(1))) unsigned int*)(gA0 + k0),
                                         (__attribute__((address_space(3))) unsigned int*)(As + sh0), 16, 0, 0);
        __builtin_amdgcn_global_load_lds((const __attribute__((address_space(1))) unsigned int*)(gA1 + k0),
                                         (__attribute__((address_space(3))) unsigned int*)(As + sh1), 16, 0, 0);
        __builtin_amdgcn_global_load_lds((const __attribute__((address_space(1))) unsigned int*)(gB0 + k0),
                                         (__attribute__((address_space(3))) unsigned int*)(Bs + sh0), 16, 0, 0);
        __builtin_amdgcn_global_load_lds((const __attribute__((address_space(1))) unsigned int*)(gB1 + k0),
                                         (__attribute__((address_space(3))) unsigned int*)(Bs + sh1), 16, 0, 0);
        __syncthreads();
        short8 af[4], bfr[4];
        #pragma unroll
        for (int m = 0; m < 4; ++m)
            af[m] = *reinterpret_cast<const short8*>(&As[(wm * 64 + m * 16 + lr) * 32 + lg * 8]);
        #pragma unroll
        for (int n = 0; n < 4; ++n)
            bfr[n] = *reinterpret_cast<const short8*>(&Bs[(wn * 64 + n * 16 + lr) * 32 + lg * 8]);
        #pragma unroll
        for (int m = 0; m < 4; ++m)
            #pragma unroll
            for (int n = 0; n < 4; ++n)
                acc[m][n] = __builtin_amdgcn_mfma_f32_16x16x32_bf16(af[m], bfr[n], acc[m][n], 0, 0, 0);
    }
    #pragma unroll
    for (int m = 0; m < 4; ++m) {
        #pragma unroll
        for (int n = 0; n < 4; ++n) {
            const int col = n0 + wn * 64 + n * 16 + lr;
            #pragma unroll
            for (int r = 0; r < 4; ++r) {
                const int row = m0 + wm * 64 + m * 16 + lg * 4 + r;
                float v = acc[m][n][r];
                if (OUT_MODE == 0) {
                    ((float*)Cout)[(long)row * N + col] = v;
                } else {
                    const int which = col >> 11;           // 0=Q 1=K 2=V (wave-uniform per n)
                    const int h = (col >> 7) & 15;
                    const int d = col & 127;
                    const int b = row >> 11, s = row & 2047;
                    ((ushort_t*)Cout)[(long)which * M * 2048 +
                                      (((long)(b * 16 + h)) * 2048 + s) * 128 + d] = f2bf(v);
                }
            }
        }
    }
}

// ---------------- RoPE in-place on packed Q|K ([2, B*H, S, 128] contiguous) ----------------
__global__ void rope_kernel(ushort_t* __restrict__ X, const float* __restrict__ fc,
                            const float* __restrict__ fs, int total8) {
    int i = blockIdx.x * blockDim.x + threadIdx.x;
    if (i >= total8) return;
    const int s_idx = (i >> 4) & 2047;      // row = (..)*2048 + s, 16 vec8 per row
    const int i0 = (i & 15) * 4;            // freq pair base within head
    const long base = (long)i * 8;
    short8 v = *reinterpret_cast<const short8*>(X + base);
    short8 o;
    #pragma unroll
    for (int p = 0; p < 4; ++p) {
        float c  = fc[(long)s_idx * 64 + i0 + p];
        float sn = fs[(long)s_idx * 64 + i0 + p];
        float x0 = bf2f(v[2 * p]), x1 = bf2f(v[2 * p + 1]);
        o[2 * p]     = (short)f2bf(x0 * c - x1 * sn);
        o[2 * p + 1] = (short)f2bf(x0 * sn + x1 * c);
    }
    *reinterpret_cast<short8*>(X + base) = o;
}

// ---------------- V transpose: Vp[B*H, S, 128] -> Vt[B*H, 128, S] ----------------
__global__ void vtrans_kernel(const ushort_t* __restrict__ Vp, ushort_t* __restrict__ Vt,
                              int S) {
    const int bh = blockIdx.y;
    const int s0 = blockIdx.x * 16 + ((threadIdx.x >> 7) * 8);
    const int d = threadIdx.x & 127;
    const ushort_t* src = Vp + (long)bh * S * 128;
    short8 o;
    #pragma unroll
    for (int i = 0; i < 8; ++i)
        o[i] = (short)src[(long)(s0 + i) * 128 + d];
    *reinterpret_cast<short8*>(Vt + ((long)bh * 128 + d) * S + s0) = o;
}

// ---------------- causal flash attention (KVB=64, folded q-tiles: uniform work) ----------------
// grid: (S/128, B*H). Block bx does q-tiles bx and (nq-1-bx) -> exactly nq+1 kv-tiles total.
__global__ __launch_bounds__(256) void attn_kernel(const ushort_t* __restrict__ Qp,
                                                   const ushort_t* __restrict__ Kp,
                                                   const ushort_t* __restrict__ Vtg,
                                                   ushort_t* __restrict__ O,
                                                   int S, int H) {
    __shared__ __align__(16) ushort_t Ks[64][136];
    __shared__ __align__(16) ushort_t Vs[128][72];
    __shared__ __align__(16) ushort_t Pl[4][16][72];
    const int t = threadIdx.x, wid = t >> 6, lane = t & 63;
    const int lr = lane & 15, lg = lane >> 4;
    const int bh = blockIdx.y;
    const int b = bh / H, h = bh % H;
    const ushort_t* Qh = Qp + (long)bh * S * 128;
    const ushort_t* Kh = Kp + (long)bh * S * 128;
    const ushort_t* Vth = Vtg + (long)bh * 128 * S;
    const int nq = S / 64;
    const float scale = 0.08838834764831845f;

    // staging maps: K tile is contiguous 16KB; thread t covers bytes [t*64, t*64+64)
    const int ksr = t >> 2;
    const int ksc = (t & 3) * 32;
    const int vsr = t & 127;
    const int vsc = (t >> 7) * 32;

    for (int qsel = 0; qsel < 2; ++qsel) {
        const int qt = qsel ? (nq - 1 - blockIdx.x) : blockIdx.x;
        const int qb0 = qt * 64;

        const int qrow = qb0 + wid * 16 + lr;
        short8 qf[4];
        #pragma unroll
        for (int kk = 0; kk < 4; ++kk)
            qf[kk] = *reinterpret_cast<const short8*>(Qh + (long)qrow * 128 + kk * 32 + lg * 8);

        f32x4 oacc[8] = {};
        float mrow[4], lsum[4];
        #pragma unroll
        for (int r = 0; r < 4; ++r) { mrow[r] = -INFINITY; lsum[r] = 0.f; }

        const int nkt = qt + 1;
        for (int kt = 0; kt < nkt; ++kt) {
            const int kv0 = kt * 64;
            __syncthreads();
            const ushort_t* kgp = Kh + (long)kv0 * 128 + t * 32;
            #pragma unroll
            for (int j = 0; j < 4; ++j)
                *reinterpret_cast<short8*>(&Ks[ksr][ksc + j * 8]) = *reinterpret_cast<const short8*>(kgp + j * 8);
            const ushort_t* vgp = Vth + (long)vsr * S + kv0 + vsc;
            #pragma unroll
            for (int j = 0; j < 4; ++j)
                *reinterpret_cast<short8*>(&Vs[vsr][vsc + j * 8]) = *reinterpret_cast<const short8*>(vgp + j * 8);
            __syncthreads();

            f32x4 sacc[4] = {};
            #pragma unroll
            for (int kk = 0; kk < 4; ++kk) {
                #pragma unroll
                for (int n = 0; n < 4; ++n) {
                    short8 kf = *reinterpret_cast<const short8*>(&Ks[n * 16 + lr][kk * 32 + lg * 8]);
                    sacc[n] = __builtin_amdgcn_mfma_f32_16x16x32_bf16(qf[kk], kf, sacc[n], 0, 0, 0);
                }
            }
            float sv[4][4];
            const int myq = qb0 + wid * 16 + lg * 4;
            #pragma unroll
            for (int n = 0; n < 4; ++n) {
                int kcol = kv0 + n * 16 + lr;
                #pragma unroll
                for (int r = 0; r < 4; ++r) {
                    float xv = sacc[n][r] * scale;
                    sv[n][r] = (kcol > myq + r) ? -1e9f : xv;
                }
            }
            float alpha[4];
            #pragma unroll
            for (int r = 0; r < 4; ++r) {
                float mx = fmaxf(fmaxf(sv[0][r], sv[1][r]), fmaxf(sv[2][r], sv[3][r]));
                #pragma unroll
                for (int off = 1; off < 16; off <<= 1)
                    mx = fmaxf(mx, __shfl_xor(mx, off));
                float mnew = fmaxf(mrow[r], mx);
                alpha[r] = __expf(mrow[r] - mnew);
                float ts = 0.f;
                #pragma unroll
                for (int n = 0; n < 4; ++n) {
                    float p = __expf(sv[n][r] - mnew);
                    sv[n][r] = p;
                    ts += p;
                }
                #pragma unroll
                for (int off = 1; off < 16; off <<= 1)
                    ts += __shfl_xor(ts, off);
                lsum[r] = lsum[r] * alpha[r] + ts;
                mrow[r] = mnew;
            }
            #pragma unroll
            for (int f = 0; f < 8; ++f)
                #pragma unroll
                for (int r = 0; r < 4; ++r)
                    oacc[f][r] *= alpha[r];
            #pragma unroll
            for (int n = 0; n < 4; ++n)
                #pragma unroll
                for (int r = 0; r < 4; ++r)
                    Pl[wid][lg * 4 + r][n * 16 + lr] = f2bf(sv[n][r]);
            __asm volatile("" ::: "memory");
            short8 pf[2];
            #pragma unroll
            for (int ks = 0; ks < 2; ++ks)
                pf[ks] = *reinterpret_cast<const short8*>(&Pl[wid][lr][ks * 32 + lg * 8]);
            #pragma unroll
            for (int f = 0; f < 8; ++f) {
                #pragma unroll
                for (int ks = 0; ks < 2; ++ks) {
                    short8 vf = *reinterpret_cast<const short8*>(&Vs[f * 16 + lr][ks * 32 + lg * 8]);
                    oacc[f] = __builtin_amdgcn_mfma_f32_16x16x32_bf16(pf[ks], vf, oacc[f], 0, 0, 0);
                }
            }
        }
        // epilogue: O in (B,S,H*128) row-major for the wo GEMM
        float inv[4];
        #pragma unroll
        for (int r = 0; r < 4; ++r) inv[r] = 1.f / lsum[r];
        ushort_t* Oh = O + (long)b * S * 2048 + h * 128;
        #pragma unroll
        for (int f = 0; f < 8; ++f) {
            #pragma unroll
            for (int r = 0; r < 4; ++r) {
                int row = qb0 + wid * 16 + lg * 4 + r;
                int col = f * 16 + lr;
                Oh[(long)row * 2048 + col] = f2bf(oacc[f][r] * inv[r]);
            }
        }
    }
}

extern "C" void kernel_launch(void* const* d_in, const int* in_sizes, int n_in,
                              void* d_out, int out_size, void* d_ws, size_t ws_size,
                              hipStream_t stream) {
    const float* x  = (const float*)d_in[0];
    const float* fc = (const float*)d_in[1];
    const float* fs = (const float*)d_in[2];
    const float* wq = (const float*)d_in[3];
    const float* wk = (const float*)d_in[4];
    const float* wv = (const float*)d_in[5];
    const float* wo = (const float*)d_in[6];
    float* out = (float*)d_out;

    const int B = 2, S = 2048, D = 2048, H = 16;
    const int M = B * S;            // 4096
    const size_t MD = (size_t)M * D;
    const size_t DD = (size_t)D * D;

    char* ws = (char*)d_ws;
    ushort_t* xbf = (ushort_t*)ws;                    // [0, 16.8MB)
    ushort_t* wqb = (ushort_t*)(ws + MD * 2);         // wq|wk|wv|wo bf16 contiguous (33.5MB)
    ushort_t* wob = wqb + 3 * DD;
    ushort_t* qp  = wqb + 4 * DD;                     // packed Q|K|V: 3 x [B*H, S, 128] (50.3MB)
    ushort_t* kp  = qp + MD;
    ushort_t* vp  = kp + MD;
    ushort_t* vtg   = xbf;                            // overlay: x dead after QKV GEMM
    ushort_t* attnb = vp;                             // overlay: Vp dead after vtrans

    // 1) converts
    cvt_kernel<<<2048, 256, 0, stream>>>(x, xbf, (int)(MD / 8));
    cvtw_kernel<<<2048, 256, 0, stream>>>(wq, wk, wv, wo, wqb, (int)(DD / 8));

    // 2) fused QKV projection, head-packed outputs
    dim3 gq(6144 / 128, M / 128);
    gemm_nt<1><<<gq, 256, 0, stream>>>(xbf, wqb, qp, M, 3 * D, D);

    // 3) RoPE in-place on packed Q|K (contiguous 2*MD elems)
    const int total8 = (int)(2 * MD / 8);
    rope_kernel<<<(total8 + 255) / 256, 256, 0, stream>>>(qp, fc, fs, total8);

    // 4) V transpose, then causal flash attention (folded: uniform work/block)
    dim3 gv(S / 16, B * H);
    vtrans_kernel<<<gv, 256, 0, stream>>>(vp, vtg, S);
    dim3 ga(S / 128, B * H);
    attn_kernel<<<ga, 256, 0, stream>>>(qp, kp, vtg, attnb, S, H);

    // 5) output projection (fp32 out)
    dim3 gg(D / 128, M / 128);
    gemm_nt<0><<<gg, 256, 0, stream>>>(attnb, wob, out, M, D, D);
}

// Round 5
// 318.512 us; speedup vs baseline: 1.3318x; 1.0944x over previous
//
#include <hip/hip_runtime.h>
#include <hip/hip_bf16.h>
#include <math.h>

typedef __attribute__((ext_vector_type(8))) short short8;
typedef __attribute__((ext_vector_type(4))) float f32x4;
typedef unsigned short ushort_t;

__device__ __forceinline__ ushort_t f2bf(float f) {
    union { float f; unsigned u; } v; v.f = f;
    unsigned r = v.u + 0x7FFF + ((v.u >> 16) & 1);
    return (ushort_t)(r >> 16);
}
__device__ __forceinline__ float bf2f(short s) {
    union { unsigned u; float f; } v; v.u = ((unsigned)(ushort_t)s) << 16;
    return v.f;
}

// ---------------- fp32 -> bf16 convert (x) ----------------
__global__ void cvt_kernel(const float* __restrict__ src, ushort_t* __restrict__ dst, int n8) {
    int i = blockIdx.x * blockDim.x + threadIdx.x;
    int stride = gridDim.x * blockDim.x;
    for (; i < n8; i += stride) {
        const float4* s = reinterpret_cast<const float4*>(src) + (size_t)i * 2;
        float4 a = s[0], b = s[1];
        short8 o;
        o[0] = (short)f2bf(a.x); o[1] = (short)f2bf(a.y);
        o[2] = (short)f2bf(a.z); o[3] = (short)f2bf(a.w);
        o[4] = (short)f2bf(b.x); o[5] = (short)f2bf(b.y);
        o[6] = (short)f2bf(b.z); o[7] = (short)f2bf(b.w);
        reinterpret_cast<short8*>(dst)[i] = o;
    }
}

// ---------------- fused weight convert: wq|wk|wv|wo -> contiguous bf16 ----------------
__global__ void cvtw_kernel(const float* __restrict__ w0, const float* __restrict__ w1,
                            const float* __restrict__ w2, const float* __restrict__ w3,
                            ushort_t* __restrict__ dst, int dd8) {
    int i = blockIdx.x * blockDim.x + threadIdx.x;
    int stride = gridDim.x * blockDim.x;
    const int total = dd8 * 4;
    for (; i < total; i += stride) {
        int which = i / dd8;
        int off = i - which * dd8;
        const float* src = (which == 0) ? w0 : (which == 1) ? w1 : (which == 2) ? w2 : w3;
        const float4* s = reinterpret_cast<const float4*>(src) + (size_t)off * 2;
        float4 a = s[0], b = s[1];
        short8 o;
        o[0] = (short)f2bf(a.x); o[1] = (short)f2bf(a.y);
        o[2] = (short)f2bf(a.z); o[3] = (short)f2bf(a.w);
        o[4] = (short)f2bf(b.x); o[5] = (short)f2bf(b.y);
        o[6] = (short)f2bf(b.z); o[7] = (short)f2bf(b.w);
        reinterpret_cast<short8*>(dst)[i] = o;
    }
}

// ---------------- GEMM NT: 128x128 tile, BK=32, double-buffered, 1 barrier/K-step ----------------
// T3-minimum pipeline: stage(t+1) issued BEFORE compute(t); the single end-of-iter
// __syncthreads() drains vmcnt after the loads flew across the whole MFMA phase.
template<int OUT_MODE>
__global__ __launch_bounds__(256) void gemm_nt(const ushort_t* __restrict__ A,
                                               const ushort_t* __restrict__ Bw,
                                               void* __restrict__ Cout,
                                               int M, int N, int K) {
    __shared__ __align__(16) ushort_t As[2 * 128 * 32];
    __shared__ __align__(16) ushort_t Bs[2 * 128 * 32];
    const int t = threadIdx.x;
    const int wid = t >> 6, lane = t & 63;
    const int wm = wid >> 1, wn = wid & 1;
    const int lr = lane & 15, lg = lane >> 4;

    const int ntc = N >> 7;
    const int nwg = (M >> 7) * ntc;
    const int bid = blockIdx.y * gridDim.x + blockIdx.x;
    const int cpx = nwg >> 3;
    const int swz = (bid & 7) * cpx + (bid >> 3);
    const int m0 = (swz / ntc) * 128, n0 = (swz % ntc) * 128;

    f32x4 acc[4][4] = {};

    const int sh0 = wid * 1024 + lane * 8;
    const int sh1 = sh0 + 512;
    const int r0 = sh0 >> 5, c0 = sh0 & 31;
    const int r1 = sh1 >> 5, c1 = sh1 & 31;

    const ushort_t* gA0 = A + (long)(m0 + r0) * K + c0;
    const ushort_t* gA1 = A + (long)(m0 + r1) * K + c1;
    const ushort_t* gB0 = Bw + (long)(n0 + r0) * K + c0;
    const ushort_t* gB1 = Bw + (long)(n0 + r1) * K + c1;

    auto stage = [&](int k0, int nb) {
        ushort_t* as = As + nb * 4096;
        ushort_t* bs = Bs + nb * 4096;
        __builtin_amdgcn_global_load_lds((const __attribute__((address_space(1))) unsigned int*)(gA0 + k0),
                                         (__attribute__((address_space(3))) unsigned int*)(as + sh0), 16, 0, 0);
        __builtin_amdgcn_global_load_lds((const __attribute__((address_space(1))) unsigned int*)(gA1 + k0),
                                         (__attribute__((address_space(3))) unsigned int*)(as + sh1), 16, 0, 0);
        __builtin_amdgcn_global_load_lds((const __attribute__((address_space(1))) unsigned int*)(gB0 + k0),
                                         (__attribute__((address_space(3))) unsigned int*)(bs + sh0), 16, 0, 0);
        __builtin_amdgcn_global_load_lds((const __attribute__((address_space(1))) unsigned int*)(gB1 + k0),
                                         (__attribute__((address_space(3))) unsigned int*)(bs + sh1), 16, 0, 0);
    };

    const int nt = K >> 5;
    stage(0, 0);
    __syncthreads();            // prologue drain: tile 0 resident
    int cur = 0;

    for (int ti = 0; ti < nt; ++ti) {
        if (ti + 1 < nt) stage((ti + 1) << 5, cur ^ 1);   // prefetch next tile (overlaps MFMA)
        const ushort_t* as = As + cur * 4096;
        const ushort_t* bs = Bs + cur * 4096;
        short8 af[4], bfr[4];
        #pragma unroll
        for (int m = 0; m < 4; ++m)
            af[m] = *reinterpret_cast<const short8*>(&as[(wm * 64 + m * 16 + lr) * 32 + lg * 8]);
        #pragma unroll
        for (int n = 0; n < 4; ++n)
            bfr[n] = *reinterpret_cast<const short8*>(&bs[(wn * 64 + n * 16 + lr) * 32 + lg * 8]);
        #pragma unroll
        for (int m = 0; m < 4; ++m)
            #pragma unroll
            for (int n = 0; n < 4; ++n)
                acc[m][n] = __builtin_amdgcn_mfma_f32_16x16x32_bf16(af[m], bfr[n], acc[m][n], 0, 0, 0);
        __syncthreads();        // drains vmcnt(0): tile ti+1 resident; buf[cur] safe to overwrite
        cur ^= 1;
    }

    #pragma unroll
    for (int m = 0; m < 4; ++m) {
        #pragma unroll
        for (int n = 0; n < 4; ++n) {
            const int col = n0 + wn * 64 + n * 16 + lr;
            #pragma unroll
            for (int r = 0; r < 4; ++r) {
                const int row = m0 + wm * 64 + m * 16 + lg * 4 + r;
                float v = acc[m][n][r];
                if (OUT_MODE == 0) {
                    ((float*)Cout)[(long)row * N + col] = v;
                } else {
                    const int which = col >> 11;           // 0=Q 1=K 2=V
                    const int h = (col >> 7) & 15;
                    const int d = col & 127;
                    const int b = row >> 11, s = row & 2047;
                    ((ushort_t*)Cout)[(long)which * M * 2048 +
                                      (((long)(b * 16 + h)) * 2048 + s) * 128 + d] = f2bf(v);
                }
            }
        }
    }
}

// ---------------- RoPE in-place on packed Q|K ([2, B*H, S, 128] contiguous) ----------------
__global__ void rope_kernel(ushort_t* __restrict__ X, const float* __restrict__ fc,
                            const float* __restrict__ fs, int total8) {
    int i = blockIdx.x * blockDim.x + threadIdx.x;
    if (i >= total8) return;
    const int s_idx = (i >> 4) & 2047;
    const int i0 = (i & 15) * 4;
    const long base = (long)i * 8;
    short8 v = *reinterpret_cast<const short8*>(X + base);
    short8 o;
    #pragma unroll
    for (int p = 0; p < 4; ++p) {
        float c  = fc[(long)s_idx * 64 + i0 + p];
        float sn = fs[(long)s_idx * 64 + i0 + p];
        float x0 = bf2f(v[2 * p]), x1 = bf2f(v[2 * p + 1]);
        o[2 * p]     = (short)f2bf(x0 * c - x1 * sn);
        o[2 * p + 1] = (short)f2bf(x0 * sn + x1 * c);
    }
    *reinterpret_cast<short8*>(X + base) = o;
}

// ---------------- V transpose: Vp[B*H, S, 128] -> Vt[B*H, 128, S] ----------------
__global__ void vtrans_kernel(const ushort_t* __restrict__ Vp, ushort_t* __restrict__ Vt,
                              int S) {
    const int bh = blockIdx.y;
    const int s0 = blockIdx.x * 16 + ((threadIdx.x >> 7) * 8);
    const int d = threadIdx.x & 127;
    const ushort_t* src = Vp + (long)bh * S * 128;
    short8 o;
    #pragma unroll
    for (int i = 0; i < 8; ++i)
        o[i] = (short)src[(long)(s0 + i) * 128 + d];
    *reinterpret_cast<short8*>(Vt + ((long)bh * 128 + d) * S + s0) = o;
}

// ---------------- causal flash attention (folded, T14 async-STAGE K/V) ----------------
// grid: (S/128, B*H). Block bx does q-tiles bx and (nq-1-bx): uniform work.
// K/V are reg-staged: loads for tile kt+1 issue right after the LDS-write barrier and
// land during the QK/softmax/PV compute phase (T14, +17% measured on attn).
__global__ __launch_bounds__(256, 3) void attn_kernel(const ushort_t* __restrict__ Qp,
                                                      const ushort_t* __restrict__ Kp,
                                                      const ushort_t* __restrict__ Vtg,
                                                      ushort_t* __restrict__ O,
                                                      int S, int H) {
    __shared__ __align__(16) ushort_t Ks[64][136];
    __shared__ __align__(16) ushort_t Vs[128][72];
    __shared__ __align__(16) ushort_t Pl[4][16][72];
    const int t = threadIdx.x, wid = t >> 6, lane = t & 63;
    const int lr = lane & 15, lg = lane >> 4;
    const int bh = blockIdx.y;
    const int b = bh / H, h = bh % H;
    const ushort_t* Qh = Qp + (long)bh * S * 128;
    const ushort_t* Kh = Kp + (long)bh * S * 128;
    const ushort_t* Vth = Vtg + (long)bh * 128 * S;
    const int nq = S / 64;
    const float scale = 0.08838834764831845f;

    const int ksr = t >> 2;
    const int ksc = (t & 3) * 32;
    const int vsr = t & 127;
    const int vsc = (t >> 7) * 32;

    for (int qsel = 0; qsel < 2; ++qsel) {
        const int qt = qsel ? (nq - 1 - blockIdx.x) : blockIdx.x;
        const int qb0 = qt * 64;

        const int qrow = qb0 + wid * 16 + lr;
        short8 qf[4];
        #pragma unroll
        for (int kk = 0; kk < 4; ++kk)
            qf[kk] = *reinterpret_cast<const short8*>(Qh + (long)qrow * 128 + kk * 32 + lg * 8);

        f32x4 oacc[8] = {};
        float mrow[4], lsum[4];
        #pragma unroll
        for (int r = 0; r < 4; ++r) { mrow[r] = -INFINITY; lsum[r] = 0.f; }

        const int nkt = qt + 1;

        // prologue: prefetch tile 0 into regs
        short8 kreg[4], vreg[4];
        {
            const ushort_t* kgp = Kh + t * 32;
            const ushort_t* vgp = Vth + (long)vsr * S + vsc;
            #pragma unroll
            for (int j = 0; j < 4; ++j) kreg[j] = *reinterpret_cast<const short8*>(kgp + j * 8);
            #pragma unroll
            for (int j = 0; j < 4; ++j) vreg[j] = *reinterpret_cast<const short8*>(vgp + j * 8);
        }

        for (int kt = 0; kt < nkt; ++kt) {
            const int kv0 = kt * 64;
            __syncthreads();     // prev iter's LDS reads complete before overwrite
            #pragma unroll
            for (int j = 0; j < 4; ++j)
                *reinterpret_cast<short8*>(&Ks[ksr][ksc + j * 8]) = kreg[j];
            #pragma unroll
            for (int j = 0; j < 4; ++j)
                *reinterpret_cast<short8*>(&Vs[vsr][vsc + j * 8]) = vreg[j];
            __syncthreads();     // tile kt visible to all waves
            if (kt + 1 < nkt) {  // prefetch tile kt+1 (lands during compute below)
                const ushort_t* kgp = Kh + (long)(kv0 + 64) * 128 + t * 32;
                const ushort_t* vgp = Vth + (long)vsr * S + kv0 + 64 + vsc;
                #pragma unroll
                for (int j = 0; j < 4; ++j) kreg[j] = *reinterpret_cast<const short8*>(kgp + j * 8);
                #pragma unroll
                for (int j = 0; j < 4; ++j) vreg[j] = *reinterpret_cast<const short8*>(vgp + j * 8);
            }

            f32x4 sacc[4] = {};
            #pragma unroll
            for (int kk = 0; kk < 4; ++kk) {
                #pragma unroll
                for (int n = 0; n < 4; ++n) {
                    short8 kf = *reinterpret_cast<const short8*>(&Ks[n * 16 + lr][kk * 32 + lg * 8]);
                    sacc[n] = __builtin_amdgcn_mfma_f32_16x16x32_bf16(qf[kk], kf, sacc[n], 0, 0, 0);
                }
            }
            float sv[4][4];
            const int myq = qb0 + wid * 16 + lg * 4;
            #pragma unroll
            for (int n = 0; n < 4; ++n) {
                int kcol = kv0 + n * 16 + lr;
                #pragma unroll
                for (int r = 0; r < 4; ++r) {
                    float xv = sacc[n][r] * scale;
                    sv[n][r] = (kcol > myq + r) ? -1e9f : xv;
                }
            }
            float alpha[4];
            #pragma unroll
            for (int r = 0; r < 4; ++r) {
                float mx = fmaxf(fmaxf(sv[0][r], sv[1][r]), fmaxf(sv[2][r], sv[3][r]));
                #pragma unroll
                for (int off = 1; off < 16; off <<= 1)
                    mx = fmaxf(mx, __shfl_xor(mx, off));
                float mnew = fmaxf(mrow[r], mx);
                alpha[r] = __expf(mrow[r] - mnew);
                float ts = 0.f;
                #pragma unroll
                for (int n = 0; n < 4; ++n) {
                    float p = __expf(sv[n][r] - mnew);
                    sv[n][r] = p;
                    ts += p;
                }
                #pragma unroll
                for (int off = 1; off < 16; off <<= 1)
                    ts += __shfl_xor(ts, off);
                lsum[r] = lsum[r] * alpha[r] + ts;
                mrow[r] = mnew;
            }
            #pragma unroll
            for (int f = 0; f < 8; ++f)
                #pragma unroll
                for (int r = 0; r < 4; ++r)
                    oacc[f][r] *= alpha[r];
            #pragma unroll
            for (int n = 0; n < 4; ++n)
                #pragma unroll
                for (int r = 0; r < 4; ++r)
                    Pl[wid][lg * 4 + r][n * 16 + lr] = f2bf(sv[n][r]);
            __asm volatile("" ::: "memory");
            short8 pf[2];
            #pragma unroll
            for (int ks = 0; ks < 2; ++ks)
                pf[ks] = *reinterpret_cast<const short8*>(&Pl[wid][lr][ks * 32 + lg * 8]);
            #pragma unroll
            for (int f = 0; f < 8; ++f) {
                #pragma unroll
                for (int ks = 0; ks < 2; ++ks) {
                    short8 vf = *reinterpret_cast<const short8*>(&Vs[f * 16 + lr][ks * 32 + lg * 8]);
                    oacc[f] = __builtin_amdgcn_mfma_f32_16x16x32_bf16(pf[ks], vf, oacc[f], 0, 0, 0);
                }
            }
        }
        float inv[4];
        #pragma unroll
        for (int r = 0; r < 4; ++r) inv[r] = 1.f / lsum[r];
        ushort_t* Oh = O + (long)b * S * 2048 + h * 128;
        #pragma unroll
        for (int f = 0; f < 8; ++f) {
            #pragma unroll
            for (int r = 0; r < 4; ++r) {
                int row = qb0 + wid * 16 + lg * 4 + r;
                int col = f * 16 + lr;
                Oh[(long)row * 2048 + col] = f2bf(oacc[f][r] * inv[r]);
            }
        }
    }
}

extern "C" void kernel_launch(void* const* d_in, const int* in_sizes, int n_in,
                              void* d_out, int out_size, void* d_ws, size_t ws_size,
                              hipStream_t stream) {
    const float* x  = (const float*)d_in[0];
    const float* fc = (const float*)d_in[1];
    const float* fs = (const float*)d_in[2];
    const float* wq = (const float*)d_in[3];
    const float* wk = (const float*)d_in[4];
    const float* wv = (const float*)d_in[5];
    const float* wo = (const float*)d_in[6];
    float* out = (float*)d_out;

    const int B = 2, S = 2048, D = 2048, H = 16;
    const int M = B * S;            // 4096
    const size_t MD = (size_t)M * D;
    const size_t DD = (size_t)D * D;

    char* ws = (char*)d_ws;
    ushort_t* xbf = (ushort_t*)ws;
    ushort_t* wqb = (ushort_t*)(ws + MD * 2);
    ushort_t* wob = wqb + 3 * DD;
    ushort_t* qp  = wqb + 4 * DD;
    ushort_t* kp  = qp + MD;
    ushort_t* vp  = kp + MD;
    ushort_t* vtg   = xbf;           // overlay: x dead after QKV GEMM
    ushort_t* attnb = vp;            // overlay: Vp dead after vtrans

    cvt_kernel<<<2048, 256, 0, stream>>>(x, xbf, (int)(MD / 8));
    cvtw_kernel<<<2048, 256, 0, stream>>>(wq, wk, wv, wo, wqb, (int)(DD / 8));

    dim3 gq(6144 / 128, M / 128);
    gemm_nt<1><<<gq, 256, 0, stream>>>(xbf, wqb, qp, M, 3 * D, D);

    const int total8 = (int)(2 * MD / 8);
    rope_kernel<<<(total8 + 255) / 256, 256, 0, stream>>>(qp, fc, fs, total8);

    dim3 gv(S / 16, B * H);
    vtrans_kernel<<<gv, 256, 0, stream>>>(vp, vtg, S);
    dim3 ga(S / 128, B * H);
    attn_kernel<<<ga, 256, 0, stream>>>(qp, kp, vtg, attnb, S, H);

    dim3 gg(D / 128, M / 128);
    gemm_nt<0><<<gg, 256, 0, stream>>>(attnb, wob, out, M, D, D);
}